// Round 3
// baseline (1165.037 us; speedup 1.0000x reference)
//
#include <hip/hip_runtime.h>
#include <math.h>

typedef __attribute__((ext_vector_type(8))) short bf16x8;  // 8 bf16 = 4 VGPR
typedef __attribute__((ext_vector_type(4))) short bf16x4;  // 8 B
typedef __attribute__((ext_vector_type(4))) float f32x4;   // C/D frag

#define SSCL (0.08838834764831845f * 1.4426950408889634f)  // 1/sqrt(128) * log2(e)

__device__ __forceinline__ short f2bf(float f) {
    union { float f; unsigned u; } x; x.f = f;
    unsigned r = x.u + 0x7fffu + ((x.u >> 16) & 1u);
    return (short)(r >> 16);
}
__device__ __forceinline__ float bf2f(short s) {
    union { unsigned u; float f; } x;
    x.u = ((unsigned)(unsigned short)s) << 16;
    return x.f;
}

typedef const __attribute__((address_space(1))) unsigned int* gas_ptr;
typedef __attribute__((address_space(3))) unsigned int* las_ptr;
__device__ __forceinline__ void async_copy16(const void* g, void* l) {
    __builtin_amdgcn_global_load_lds((gas_ptr)g, (las_ptr)l, 16, 0, 0);
}

// ---------------------------------------------------------------------------
// fp32 -> bf16 conversion pre-pass (vectorized, grid-stride). n4 = nelem/4.
// ---------------------------------------------------------------------------
__global__ __launch_bounds__(256)
void cvt_kernel(const float* __restrict__ src, short* __restrict__ dst, int n4) {
    int i = blockIdx.x * 256 + threadIdx.x;
    const int stride = gridDim.x * 256;
    for (; i < n4; i += stride) {
        float4 v = ((const float4*)src)[i];
        bf16x4 o;
        o[0] = f2bf(v.x); o[1] = f2bf(v.y); o[2] = f2bf(v.z); o[3] = f2bf(v.w);
        ((bf16x4*)dst)[i] = o;
    }
}

// ---------------------------------------------------------------------------
// NT GEMM (m97 pattern): D[m,n] = sum_k A[m,k]*B[n,k], bf16 in, fp32 acc.
// QKV=1: blockIdx.x in [0,48), sel=bx>>4: sel0 -> D16 (bf16, Q scratch),
//        sel1/2 -> Dk/Dv fp32 with kv-append row map m + ((m>>11)+1)*2048.
// QKV=0: blockIdx.x in [0,16), D = Df fp32 plain [4096,2048].
// ---------------------------------------------------------------------------
template<int QKV>
__global__ __launch_bounds__(256)
void gemm_kernel(const short* __restrict__ A,
                 const short* __restrict__ B0, const short* __restrict__ B1,
                 const short* __restrict__ B2,
                 short* __restrict__ D16, float* __restrict__ Dk,
                 float* __restrict__ Dv, float* __restrict__ Df) {
    __shared__ short As[128 * 64];
    __shared__ short Bs[128 * 64];
    const int tid = threadIdx.x, w = tid >> 6, ln = tid & 63;
    const int col = ln & 15, quad = ln >> 4;
    const int sel = QKV ? (blockIdx.x >> 4) : 0;
    const int tn = (blockIdx.x & 15) * 128;
    const int tm = blockIdx.y * 128;
    const short* B = (sel == 0) ? B0 : ((sel == 1) ? B1 : B2);

    const int wm = (w >> 1) * 64, wn = (w & 1) * 64;
    const int srow = ln >> 3, scol = (ln & 7) * 8;

    f32x4 acc[4][4];
    for (int i = 0; i < 4; ++i)
        for (int j = 0; j < 4; ++j)
            for (int e = 0; e < 4; ++e) acc[i][j][e] = 0.f;

    for (int k0 = 0; k0 < 2048; k0 += 64) {
        #pragma unroll
        for (int i = 0; i < 4; ++i) {
            int chunk = i * 4 + w;
            int row = chunk * 8 + srow;
            async_copy16(&A[(tm + row) * 2048 + k0 + scol], &As[chunk * 512]);
            async_copy16(&B[(tn + row) * 2048 + k0 + scol], &Bs[chunk * 512]);
        }
        asm volatile("s_waitcnt vmcnt(0)" ::: "memory");
        __syncthreads();
        #pragma unroll
        for (int kk = 0; kk < 2; ++kk) {
            bf16x8 af[4], bfr[4];
            #pragma unroll
            for (int i = 0; i < 4; ++i)
                af[i] = *(const bf16x8*)&As[(wm + i * 16 + col) * 64 + kk * 32 + quad * 8];
            #pragma unroll
            for (int j = 0; j < 4; ++j)
                bfr[j] = *(const bf16x8*)&Bs[(wn + j * 16 + col) * 64 + kk * 32 + quad * 8];
            __builtin_amdgcn_s_setprio(1);
            #pragma unroll
            for (int i = 0; i < 4; ++i)
                #pragma unroll
                for (int j = 0; j < 4; ++j)
                    acc[i][j] = __builtin_amdgcn_mfma_f32_16x16x32_bf16(af[i], bfr[j], acc[i][j], 0, 0, 0);
            __builtin_amdgcn_s_setprio(0);
        }
        __syncthreads();
    }
    // epilogue: C/D layout col = lane&15, row = quad*4 + reg
    for (int i = 0; i < 4; ++i)
        for (int j = 0; j < 4; ++j)
            for (int r = 0; r < 4; ++r) {
                int m = tm + wm + i * 16 + quad * 4 + r;
                int n = tn + wn + j * 16 + col;
                float v = acc[i][j][r];
                if (QKV) {
                    if (sel == 0) {
                        D16[m * 2048 + n] = f2bf(v);
                    } else {
                        int orow = m + ((m >> 11) + 1) * 2048;
                        float* D = (sel == 1) ? Dk : Dv;
                        D[orow * 2048 + n] = v;
                    }
                } else {
                    Df[m * 2048 + n] = v;
                }
            }
}

// ---------------------------------------------------------------------------
// V prep: fp32 vall [b][4096][16][128] -> bf16 transposed Vtg [b][h][128][4096],
// XOR-swizzled within each 64-key tile: key-in-tile index kr stored at
// kr ^ ((d&7)<<3) so that attention can global_load_lds the tile linearly and
// ds_read_b128 it conflict-free. One block per (64-key tile, h, b).
// ---------------------------------------------------------------------------
__global__ __launch_bounds__(256)
void prep_v(const float* __restrict__ Vall, short* __restrict__ Vtg) {
    __shared__ short L[64 * 132];
    const int tid = threadIdx.x;
    const int k0 = blockIdx.x * 64;
    const int h = blockIdx.y, b = blockIdx.z;
    const float* Vb = Vall + ((size_t)(b * 4096) * 16 + h) * 128;
    short* Vo = Vtg + ((size_t)(b * 16 + h) * 128) * 4096;
    #pragma unroll
    for (int i = 0; i < 8; ++i) {
        int idx = i * 256 + tid;
        int r = idx >> 5, c4 = (idx & 31) * 4;
        float4 v = *(const float4*)&Vb[(size_t)(k0 + r) * 2048 + c4];
        bf16x4 o4;
        o4[0] = f2bf(v.x); o4[1] = f2bf(v.y); o4[2] = f2bf(v.z); o4[3] = f2bf(v.w);
        *(bf16x4*)&L[r * 132 + c4] = o4;
    }
    __syncthreads();
    #pragma unroll
    for (int i = 0; i < 8; ++i) {
        int idx = i * 256 + tid;
        int d = idx >> 4, kc4 = (idx & 15) * 4;
        bf16x4 o4;
        o4[0] = L[(kc4 + 0) * 132 + d];
        o4[1] = L[(kc4 + 1) * 132 + d];
        o4[2] = L[(kc4 + 2) * 132 + d];
        o4[3] = L[(kc4 + 3) * 132 + d];
        *(bf16x4*)&Vo[(size_t)d * 4096 + k0 + (kc4 ^ ((d & 7) << 3))] = o4;
    }
}

// ---------------------------------------------------------------------------
// MFMA flash attention, 2 q-frags per wave. grid (bh=32, qtile=16), block 256.
// Block: 128 q-rows of (b,h) = bh; wave w owns rows s0+w*16..+15 (frag 0)
// and s0+64+w*16..+15 (frag 1). K/V LDS reads are shared by both frags
// (2x MFMA per staged byte vs the 64-row version). Grid order puts all
// q-tiles of one (b,h) on the same XCD (linear id % 8 == bh % 8) for K/V L2
// locality. Frag-0-fully-masked tail tiles skipped via wave-uniform guard.
// ---------------------------------------------------------------------------
__global__ __launch_bounds__(256)
void attn_mfma(const short* __restrict__ Q, const float* __restrict__ Kall,
               const short* __restrict__ Vtg, short* __restrict__ Ot) {
    __shared__ short Ks[64 * 128];
    __shared__ short Vs[128 * 64];
    __shared__ short Ps[2 * 4 * 16 * 72];
    const int tid = threadIdx.x, w = tid >> 6, ln = tid & 63;
    const int col = ln & 15, quad = ln >> 4;
    const int bh = blockIdx.x;
    const int b = bh >> 4, h = bh & 15;
    const int s0 = blockIdx.y * 128;
    const int xk = (col & 7) << 3;   // fragment-read swizzle term

    // Q fragments (one-time), 2 per wave
    bf16x8 qf[2][4];
    #pragma unroll
    for (int f = 0; f < 2; ++f) {
        const int qr = (b * 2048 + s0 + f * 64 + w * 16 + col) * 2048 + h * 128;
        #pragma unroll
        for (int ks = 0; ks < 4; ++ks)
            qf[f][ks] = *(const bf16x8*)&Q[qr + ks * 32 + quad * 8];
    }
    f32x4 o[2][8];
    #pragma unroll
    for (int f = 0; f < 2; ++f)
        #pragma unroll
        for (int i = 0; i < 8; ++i)
            for (int e = 0; e < 4; ++e) o[f][i][e] = 0.f;
    float mr[2][4], lr[2][4];
    #pragma unroll
    for (int f = 0; f < 2; ++f)
        #pragma unroll
        for (int r = 0; r < 4; ++r) { mr[f][r] = -1e30f; lr[f][r] = 0.f; }

    const float* Kb = Kall + ((size_t)(b * 4096) * 16 + h) * 128;
    const short* Vb = Vtg + ((size_t)(b * 16 + h) * 128) * 4096;
    short* P0w = &Ps[w * 1152];
    short* P1w = &Ps[4608 + w * 1152];

    // per-thread staging bases (hoisted)
    const int vd = (ln >> 3);
    const int vkofs = (ln & 7) * 8;
    const int kr0 = tid >> 5;
    const int kc4 = (tid & 31) * 4;
    const int kswz = (kc4 ^ ((kr0 & 7) << 3));

    const int ntiles = 34 + 2 * blockIdx.y;   // (2048 + s0 + 128)/64
    for (int t = 0; t < ntiles; ++t) {
        const int k0 = t * 64;
        // ---- stage V tile (16 KB, async direct-to-LDS, pre-swizzled) ----
        #pragma unroll
        for (int i = 0; i < 4; ++i) {
            int ch = i * 4 + w;
            async_copy16(&Vb[(size_t)(ch * 8 + vd) * 4096 + k0 + vkofs], &Vs[ch * 512]);
        }
        // ---- stage K tile (fp32 -> bf16, swizzled reg-stage) ----
        #pragma unroll
        for (int i = 0; i < 8; ++i) {
            int kr = i * 8 + kr0;
            float4 kv = *(const float4*)&Kb[(size_t)(k0 + kr) * 2048 + kc4];
            bf16x4 kb4;
            kb4[0] = f2bf(kv.x); kb4[1] = f2bf(kv.y);
            kb4[2] = f2bf(kv.z); kb4[3] = f2bf(kv.w);
            *(bf16x4*)&Ks[kr * 128 + kswz] = kb4;
        }
        asm volatile("s_waitcnt vmcnt(0)" ::: "memory");
        __syncthreads();

        const bool act0 = (k0 <= 2048 + s0 + w * 16 + 15);  // wave-uniform

        // ---- QK^T for both frags, kf reads shared ----
        f32x4 s4[2][4];
        #pragma unroll
        for (int f = 0; f < 2; ++f)
            #pragma unroll
            for (int j = 0; j < 4; ++j)
                for (int e = 0; e < 4; ++e) s4[f][j][e] = 0.f;
        #pragma unroll
        for (int ks = 0; ks < 4; ++ks) {
            const int dofs = (ks * 32 + quad * 8) ^ xk;
            bf16x8 kf[4];
            #pragma unroll
            for (int j = 0; j < 4; ++j)
                kf[j] = *(const bf16x8*)&Ks[(j * 16 + col) * 128 + dofs];
            __builtin_amdgcn_s_setprio(1);
            #pragma unroll
            for (int j = 0; j < 4; ++j)
                s4[0][j] = __builtin_amdgcn_mfma_f32_16x16x32_bf16(qf[0][ks], kf[j], s4[0][j], 0, 0, 0);
            #pragma unroll
            for (int j = 0; j < 4; ++j)
                s4[1][j] = __builtin_amdgcn_mfma_f32_16x16x32_bf16(qf[1][ks], kf[j], s4[1][j], 0, 0, 0);
            __builtin_amdgcn_s_setprio(0);
        }

        // ---- online softmax per frag (scaled base-2 domain) ----
        #pragma unroll
        for (int f = 0; f < 2; ++f) {
            if (f == 0 && !act0) continue;           // frag 0 fully masked
            const int qbase = 2048 + s0 + f * 64 + w * 16;
            const bool full = (k0 + 63 <= qbase);    // wave-uniform
            float p[4][4];
            if (full) {
                #pragma unroll
                for (int j = 0; j < 4; ++j)
                    #pragma unroll
                    for (int r = 0; r < 4; ++r) p[j][r] = s4[f][j][r] * SSCL;
            } else {
                #pragma unroll
                for (int j = 0; j < 4; ++j) {
                    int kp = k0 + j * 16 + col;
                    #pragma unroll
                    for (int r = 0; r < 4; ++r) {
                        int qp = qbase + quad * 4 + r;
                        p[j][r] = (kp <= qp) ? s4[f][j][r] * SSCL : -1e30f;
                    }
                }
            }
            #pragma unroll
            for (int r = 0; r < 4; ++r) {
                float mx = fmaxf(fmaxf(p[0][r], p[1][r]), fmaxf(p[2][r], p[3][r]));
                mx = fmaxf(mx, __shfl_xor(mx, 1));
                mx = fmaxf(mx, __shfl_xor(mx, 2));
                mx = fmaxf(mx, __shfl_xor(mx, 4));
                mx = fmaxf(mx, __shfl_xor(mx, 8));
                float mn = fmaxf(mr[f][r], mx);
                float al = exp2f(mr[f][r] - mn);
                mr[f][r] = mn;
                float rs = 0.f;
                #pragma unroll
                for (int j = 0; j < 4; ++j) { p[j][r] = exp2f(p[j][r] - mn); rs += p[j][r]; }
                rs += __shfl_xor(rs, 1);
                rs += __shfl_xor(rs, 2);
                rs += __shfl_xor(rs, 4);
                rs += __shfl_xor(rs, 8);
                lr[f][r] = lr[f][r] * al + rs;
                #pragma unroll
                for (int i = 0; i < 8; ++i) o[f][i][r] *= al;
            }
            // P -> per-wave LDS (C-layout -> A-frag relayout)
            short* Pf = (f == 0) ? P0w : P1w;
            #pragma unroll
            for (int j = 0; j < 4; ++j)
                #pragma unroll
                for (int r = 0; r < 4; ++r)
                    Pf[(quad * 4 + r) * 72 + j * 16 + col] = f2bf(p[j][r]);
        }

        // ---- PV for both frags, V reads shared ----
        bf16x8 pa00 = *(const bf16x8*)&P0w[col * 72 + quad * 8];
        bf16x8 pa01 = *(const bf16x8*)&P0w[col * 72 + 32 + quad * 8];
        bf16x8 pa10 = *(const bf16x8*)&P1w[col * 72 + quad * 8];
        bf16x8 pa11 = *(const bf16x8*)&P1w[col * 72 + 32 + quad * 8];
        #pragma unroll
        for (int dt = 0; dt < 8; ++dt) {
            int row = dt * 16 + col;
            bf16x8 v0 = *(const bf16x8*)&Vs[row * 64 + ((quad * 8) ^ xk)];
            bf16x8 v1 = *(const bf16x8*)&Vs[row * 64 + ((32 + quad * 8) ^ xk)];
            __builtin_amdgcn_s_setprio(1);
            if (act0) {
                o[0][dt] = __builtin_amdgcn_mfma_f32_16x16x32_bf16(pa00, v0, o[0][dt], 0, 0, 0);
                o[0][dt] = __builtin_amdgcn_mfma_f32_16x16x32_bf16(pa01, v1, o[0][dt], 0, 0, 0);
            }
            o[1][dt] = __builtin_amdgcn_mfma_f32_16x16x32_bf16(pa10, v0, o[1][dt], 0, 0, 0);
            o[1][dt] = __builtin_amdgcn_mfma_f32_16x16x32_bf16(pa11, v1, o[1][dt], 0, 0, 0);
            __builtin_amdgcn_s_setprio(0);
        }
        __syncthreads();   // tile reads done before next overwrite
    }
    // ---- epilogue ----
    #pragma unroll
    for (int f = 0; f < 2; ++f) {
        const int orow = (b * 2048 + s0 + f * 64 + w * 16) * 2048 + h * 128;
        #pragma unroll
        for (int r = 0; r < 4; ++r) {
            float inv = 1.f / lr[f][r];
            #pragma unroll
            for (int dt = 0; dt < 8; ++dt)
                Ot[orow + (quad * 4 + r) * 2048 + dt * 16 + col] = f2bf(o[f][dt][r] * inv);
        }
    }
}

// ---------------------------------------------------------------------------
extern "C" void kernel_launch(void* const* d_in, const int* in_sizes, int n_in,
                              void* d_out, int out_size, void* d_ws, size_t ws_size,
                              hipStream_t stream) {
    const float* x  = (const float*)d_in[0];
    const float* pk = (const float*)d_in[1];
    const float* pv = (const float*)d_in[2];
    // d_in[3] = mask (unused: causal structure reproduced analytically)
    const float* wq = (const float*)d_in[4];
    const float* wk = (const float*)d_in[5];
    const float* wv = (const float*)d_in[6];
    const float* wo = (const float*)d_in[7];

    float* out  = (float*)d_out;                 // [2][2048][2048]
    float* kall = out + 8388608;                 // [2][4096][16][128]
    float* vall = out + 25165824;                // [2][4096][16][128]

    short* ws16 = (short*)d_ws;
    // 64 MiB workspace layout (overlapped lifetimes):
    short* xb  = ws16;                // [4096][2048] bf16; dead after gemm1 -> ot
    short* wqb = ws16 + 8388608;      // weights bf16; dead after gemm1
    short* wkb = ws16 + 12582912;
    short* wvb = ws16 + 16777216;
    short* wob = ws16 + 20971520;     // converted AFTER attn (region aliases Vtg)
    short* vtg = ws16 + 8388608;      // [2][16][128][4096] bf16; overlays weights
    short* qbf = ws16 + 25165824;     // [4096][2048] bf16
    short* ot  = xb;                  // alias: xb dead after gemm1

    // history -> kv cache, bit-exact fp32 (per batch: 4,194,304 floats = 16 MiB)
    hipMemcpyAsync(kall,           pk,           16777216u, hipMemcpyDeviceToDevice, stream);
    hipMemcpyAsync(kall + 8388608, pk + 4194304, 16777216u, hipMemcpyDeviceToDevice, stream);
    hipMemcpyAsync(vall,           pv,           16777216u, hipMemcpyDeviceToDevice, stream);
    hipMemcpyAsync(vall + 8388608, pv + 4194304, 16777216u, hipMemcpyDeviceToDevice, stream);

    // fp32 -> bf16 pre-pass for x and the QKV weights (wo converted later)
    cvt_kernel<<<1024, 256, 0, stream>>>(x,  xb,  2097152);
    cvt_kernel<<<512,  256, 0, stream>>>(wq, wqb, 1048576);
    cvt_kernel<<<512,  256, 0, stream>>>(wk, wkb, 1048576);
    cvt_kernel<<<512,  256, 0, stream>>>(wv, wvb, 1048576);

    // fused QKV projection: Q -> qbf (bf16), K/V chunk -> kall/vall (fp32)
    gemm_kernel<1><<<dim3(48, 32), 256, 0, stream>>>(xb, wqb, wkb, wvb,
                                                     qbf, kall, vall, nullptr);
    // V transpose+swizzle prep for MFMA attention (weights now dead)
    prep_v<<<dim3(64, 16, 2), 256, 0, stream>>>(vall, vtg);
    // MFMA flash attention (bh on x for XCD L2 locality, 128 q-rows/block)
    attn_mfma<<<dim3(32, 16), 256, 0, stream>>>(qbf, kall, vtg, ot);
    // wo conversion (vtg now dead) + output projection -> out (fp32)
    cvt_kernel<<<512, 256, 0, stream>>>(wo, wob, 1048576);
    gemm_kernel<0><<<dim3(16, 32), 256, 0, stream>>>(ot, wob, wob, wob,
                                                     nullptr, nullptr, nullptr, out);
}

// Round 4
// 858.291 us; speedup vs baseline: 1.3574x; 1.3574x over previous
//
#include <hip/hip_runtime.h>
#include <math.h>

typedef __attribute__((ext_vector_type(8))) short bf16x8;  // 8 bf16 = 4 VGPR
typedef __attribute__((ext_vector_type(4))) short bf16x4;  // 8 B
typedef __attribute__((ext_vector_type(4))) float f32x4;   // C/D frag

#define SSCL (0.08838834764831845f * 1.4426950408889634f)  // 1/sqrt(128) * log2(e)

__device__ __forceinline__ short f2bf(float f) {
    union { float f; unsigned u; } x; x.f = f;
    unsigned r = x.u + 0x7fffu + ((x.u >> 16) & 1u);
    return (short)(r >> 16);
}
__device__ __forceinline__ float bf2f(short s) {
    union { unsigned u; float f; } x;
    x.u = ((unsigned)(unsigned short)s) << 16;
    return x.f;
}

typedef const __attribute__((address_space(1))) unsigned int* gas_ptr;
typedef __attribute__((address_space(3))) unsigned int* las_ptr;
__device__ __forceinline__ void async_copy16(const void* g, void* l) {
    __builtin_amdgcn_global_load_lds((gas_ptr)g, (las_ptr)l, 16, 0, 0);
}

// ---------------------------------------------------------------------------
// fp32 -> bf16 conversion pre-pass (vectorized, grid-stride). n4 = nelem/4.
// ---------------------------------------------------------------------------
__global__ __launch_bounds__(256)
void cvt_kernel(const float* __restrict__ src, short* __restrict__ dst, int n4) {
    int i = blockIdx.x * 256 + threadIdx.x;
    const int stride = gridDim.x * 256;
    for (; i < n4; i += stride) {
        float4 v = ((const float4*)src)[i];
        bf16x4 o;
        o[0] = f2bf(v.x); o[1] = f2bf(v.y); o[2] = f2bf(v.z); o[3] = f2bf(v.w);
        ((bf16x4*)dst)[i] = o;
    }
}

// ---------------------------------------------------------------------------
// NT GEMM (m97 pattern): D[m,n] = sum_k A[m,k]*B[n,k], bf16 in, fp32 acc.
// QKV=1: blockIdx.x in [0,48), sel=bx>>4: sel0 -> D16 (bf16, Q scratch),
//        sel1/2 -> Dk/Dv fp32 with kv-append row map m + ((m>>11)+1)*2048.
// QKV=0: blockIdx.x in [0,16), D = Df fp32 plain [4096,2048].
// ---------------------------------------------------------------------------
template<int QKV>
__global__ __launch_bounds__(256)
void gemm_kernel(const short* __restrict__ A,
                 const short* __restrict__ B0, const short* __restrict__ B1,
                 const short* __restrict__ B2,
                 short* __restrict__ D16, float* __restrict__ Dk,
                 float* __restrict__ Dv, float* __restrict__ Df) {
    __shared__ short As[128 * 64];
    __shared__ short Bs[128 * 64];
    const int tid = threadIdx.x, w = tid >> 6, ln = tid & 63;
    const int col = ln & 15, quad = ln >> 4;
    const int sel = QKV ? (blockIdx.x >> 4) : 0;
    const int tn = (blockIdx.x & 15) * 128;
    const int tm = blockIdx.y * 128;
    const short* B = (sel == 0) ? B0 : ((sel == 1) ? B1 : B2);

    const int wm = (w >> 1) * 64, wn = (w & 1) * 64;
    const int srow = ln >> 3, scol = (ln & 7) * 8;

    f32x4 acc[4][4];
    for (int i = 0; i < 4; ++i)
        for (int j = 0; j < 4; ++j)
            for (int e = 0; e < 4; ++e) acc[i][j][e] = 0.f;

    for (int k0 = 0; k0 < 2048; k0 += 64) {
        #pragma unroll
        for (int i = 0; i < 4; ++i) {
            int chunk = i * 4 + w;
            int row = chunk * 8 + srow;
            async_copy16(&A[(tm + row) * 2048 + k0 + scol], &As[chunk * 512]);
            async_copy16(&B[(tn + row) * 2048 + k0 + scol], &Bs[chunk * 512]);
        }
        asm volatile("s_waitcnt vmcnt(0)" ::: "memory");
        __syncthreads();
        #pragma unroll
        for (int kk = 0; kk < 2; ++kk) {
            bf16x8 af[4], bfr[4];
            #pragma unroll
            for (int i = 0; i < 4; ++i)
                af[i] = *(const bf16x8*)&As[(wm + i * 16 + col) * 64 + kk * 32 + quad * 8];
            #pragma unroll
            for (int j = 0; j < 4; ++j)
                bfr[j] = *(const bf16x8*)&Bs[(wn + j * 16 + col) * 64 + kk * 32 + quad * 8];
            __builtin_amdgcn_s_setprio(1);
            #pragma unroll
            for (int i = 0; i < 4; ++i)
                #pragma unroll
                for (int j = 0; j < 4; ++j)
                    acc[i][j] = __builtin_amdgcn_mfma_f32_16x16x32_bf16(af[i], bfr[j], acc[i][j], 0, 0, 0);
            __builtin_amdgcn_s_setprio(0);
        }
        __syncthreads();
    }
    // epilogue: C/D layout col = lane&15, row = quad*4 + reg
    for (int i = 0; i < 4; ++i)
        for (int j = 0; j < 4; ++j)
            for (int r = 0; r < 4; ++r) {
                int m = tm + wm + i * 16 + quad * 4 + r;
                int n = tn + wn + j * 16 + col;
                float v = acc[i][j][r];
                if (QKV) {
                    if (sel == 0) {
                        D16[m * 2048 + n] = f2bf(v);
                    } else {
                        int orow = m + ((m >> 11) + 1) * 2048;
                        float* D = (sel == 1) ? Dk : Dv;
                        D[orow * 2048 + n] = v;
                    }
                } else {
                    Df[m * 2048 + n] = v;
                }
            }
}

// ---------------------------------------------------------------------------
// V prep: fp32 vall [b][4096][16][128] -> bf16 transposed Vtg [b][h][128][4096],
// XOR-swizzled within each 64-key tile: key-in-tile index kr stored at
// kr ^ ((d&7)<<3) so that attention can global_load_lds the tile linearly and
// ds_read_b128 it conflict-free. One block per (64-key tile, h, b).
// ---------------------------------------------------------------------------
__global__ __launch_bounds__(256)
void prep_v(const float* __restrict__ Vall, short* __restrict__ Vtg) {
    __shared__ short L[64 * 132];
    const int tid = threadIdx.x;
    const int k0 = blockIdx.x * 64;
    const int h = blockIdx.y, b = blockIdx.z;
    const float* Vb = Vall + ((size_t)(b * 4096) * 16 + h) * 128;
    short* Vo = Vtg + ((size_t)(b * 16 + h) * 128) * 4096;
    #pragma unroll
    for (int i = 0; i < 8; ++i) {
        int idx = i * 256 + tid;
        int r = idx >> 5, c4 = (idx & 31) * 4;
        float4 v = *(const float4*)&Vb[(size_t)(k0 + r) * 2048 + c4];
        bf16x4 o4;
        o4[0] = f2bf(v.x); o4[1] = f2bf(v.y); o4[2] = f2bf(v.z); o4[3] = f2bf(v.w);
        *(bf16x4*)&L[r * 132 + c4] = o4;
    }
    __syncthreads();
    #pragma unroll
    for (int i = 0; i < 8; ++i) {
        int idx = i * 256 + tid;
        int d = idx >> 4, kc4 = (idx & 15) * 4;
        bf16x4 o4;
        o4[0] = L[(kc4 + 0) * 132 + d];
        o4[1] = L[(kc4 + 1) * 132 + d];
        o4[2] = L[(kc4 + 2) * 132 + d];
        o4[3] = L[(kc4 + 3) * 132 + d];
        *(bf16x4*)&Vo[(size_t)d * 4096 + k0 + (kc4 ^ ((d & 7) << 3))] = o4;
    }
}

// ---------------------------------------------------------------------------
// MFMA flash attention, double-buffered pipeline. grid (bh=32, qtile=32),
// block 256 = 4 waves; 64 q-rows/block (wave w owns rows s0+w*16..+15).
// bh on grid.x => XCD = bh%8 for every qtile => all blocks sharing one
// (b,h)'s K/V land on one XCD L2 (round-3's proven FETCH win), while the
// 1024-block grid restores round-2's parallelism.
// Per tile t: issue K(t+1) global loads -> regs and V(t+1) global_load_lds
// -> Vs[p^1] BEFORE compute; compute QK/softmax/PV on buffers p; then
// convert+ds_write K(t+1) -> Ks[p^1]; one drain+barrier per tile. Load
// latency hides under compute instead of sitting on the critical path.
// ---------------------------------------------------------------------------
__global__ __launch_bounds__(256)
void attn_mfma(const short* __restrict__ Q, const float* __restrict__ Kall,
               const short* __restrict__ Vtg, short* __restrict__ Ot) {
    __shared__ short Ks[2][64 * 128];
    __shared__ short Vs[2][128 * 64];
    __shared__ short Ps[4 * 16 * 72];
    const int tid = threadIdx.x, w = tid >> 6, ln = tid & 63;
    const int col = ln & 15, quad = ln >> 4;
    const int bh = blockIdx.x;
    const int b = bh >> 4, h = bh & 15;
    const int s0 = blockIdx.y * 64;
    const int xk = (col & 7) << 3;   // fragment-read swizzle term

    // Q fragments (one-time)
    bf16x8 qf[4];
    {
        const int qr = (b * 2048 + s0 + w * 16 + col) * 2048 + h * 128;
        #pragma unroll
        for (int ks = 0; ks < 4; ++ks)
            qf[ks] = *(const bf16x8*)&Q[qr + ks * 32 + quad * 8];
    }
    f32x4 o[8];
    #pragma unroll
    for (int i = 0; i < 8; ++i)
        for (int e = 0; e < 4; ++e) o[i][e] = 0.f;
    float mr[4] = {-1e30f, -1e30f, -1e30f, -1e30f};
    float lr[4] = {0.f, 0.f, 0.f, 0.f};

    const float* Kb = Kall + ((size_t)(b * 4096) * 16 + h) * 128;
    const short* Vb = Vtg + ((size_t)(b * 16 + h) * 128) * 4096;
    short* PsW = &Ps[w * 1152];

    // per-thread staging bases (hoisted)
    const int vd = (ln >> 3);              // V: d sub-row within chunk
    const int vkofs = (ln & 7) * 8;        // V: key offset within tile
    const int kr0 = tid >> 5;              // K: key row (stride 8 over i)
    const int kc4 = (tid & 31) * 4;        // K: d offset (4 floats)
    const int kswz = (kc4 ^ ((kr0 & 7) << 3));

    const int ntiles = 33 + blockIdx.y;    // (2048 + s0 + 64)/64

    float4 kvr[8];                          // K prefetch registers (tile t+1)

    // ---- prologue: stage tile 0 into buffers 0 ----
    #pragma unroll
    for (int i = 0; i < 8; ++i)
        kvr[i] = *(const float4*)&Kb[(size_t)(i * 8 + kr0) * 2048 + kc4];
    #pragma unroll
    for (int i = 0; i < 4; ++i) {
        int ch = i * 4 + w;
        async_copy16(&Vb[(size_t)(ch * 8 + vd) * 4096 + vkofs], &Vs[0][ch * 512]);
    }
    #pragma unroll
    for (int i = 0; i < 8; ++i) {
        bf16x4 kb4;
        kb4[0] = f2bf(kvr[i].x); kb4[1] = f2bf(kvr[i].y);
        kb4[2] = f2bf(kvr[i].z); kb4[3] = f2bf(kvr[i].w);
        *(bf16x4*)&Ks[0][(i * 8 + kr0) * 128 + kswz] = kb4;
    }
    asm volatile("s_waitcnt vmcnt(0)" ::: "memory");
    __syncthreads();

    for (int t = 0; t < ntiles; ++t) {
        const int p = t & 1;
        const int k0 = t * 64;
        const bool pf = (t + 1 < ntiles);   // block-uniform prefetch guard

        // ---- issue next-tile loads (K -> regs, V -> Vs[p^1] async) ----
        if (pf) {
            const int k0n = k0 + 64;
            #pragma unroll
            for (int i = 0; i < 8; ++i)
                kvr[i] = *(const float4*)&Kb[(size_t)(k0n + i * 8 + kr0) * 2048 + kc4];
            #pragma unroll
            for (int i = 0; i < 4; ++i) {
                int ch = i * 4 + w;
                async_copy16(&Vb[(size_t)(ch * 8 + vd) * 4096 + k0n + vkofs],
                             &Vs[p ^ 1][ch * 512]);
            }
        }

        // ---- QK^T: S[quad*4+r][j*16+col] ----
        f32x4 s4[4];
        #pragma unroll
        for (int j = 0; j < 4; ++j)
            for (int e = 0; e < 4; ++e) s4[j][e] = 0.f;
        #pragma unroll
        for (int ks = 0; ks < 4; ++ks) {
            const int dofs = (ks * 32 + quad * 8) ^ xk;
            bf16x8 kf[4];
            #pragma unroll
            for (int j = 0; j < 4; ++j)
                kf[j] = *(const bf16x8*)&Ks[p][(j * 16 + col) * 128 + dofs];
            __builtin_amdgcn_s_setprio(1);
            #pragma unroll
            for (int j = 0; j < 4; ++j)
                s4[j] = __builtin_amdgcn_mfma_f32_16x16x32_bf16(qf[ks], kf[j], s4[j], 0, 0, 0);
            __builtin_amdgcn_s_setprio(0);
        }

        // ---- online softmax (scaled base-2 domain) ----
        const bool full = (k0 + 63 <= 2048 + s0 + w * 16);  // wave-uniform
        float pp[4][4];
        if (full) {
            #pragma unroll
            for (int j = 0; j < 4; ++j)
                #pragma unroll
                for (int r = 0; r < 4; ++r) pp[j][r] = s4[j][r] * SSCL;
        } else {
            #pragma unroll
            for (int j = 0; j < 4; ++j) {
                int kp = k0 + j * 16 + col;
                #pragma unroll
                for (int r = 0; r < 4; ++r) {
                    int qp = 2048 + s0 + w * 16 + quad * 4 + r;
                    pp[j][r] = (kp <= qp) ? s4[j][r] * SSCL : -1e30f;
                }
            }
        }
        #pragma unroll
        for (int r = 0; r < 4; ++r) {
            float mx = fmaxf(fmaxf(pp[0][r], pp[1][r]), fmaxf(pp[2][r], pp[3][r]));
            mx = fmaxf(mx, __shfl_xor(mx, 1));
            mx = fmaxf(mx, __shfl_xor(mx, 2));
            mx = fmaxf(mx, __shfl_xor(mx, 4));
            mx = fmaxf(mx, __shfl_xor(mx, 8));
            float mn = fmaxf(mr[r], mx);
            float al = exp2f(mr[r] - mn);
            mr[r] = mn;
            float rs = 0.f;
            #pragma unroll
            for (int j = 0; j < 4; ++j) { pp[j][r] = exp2f(pp[j][r] - mn); rs += pp[j][r]; }
            rs += __shfl_xor(rs, 1);
            rs += __shfl_xor(rs, 2);
            rs += __shfl_xor(rs, 4);
            rs += __shfl_xor(rs, 8);
            lr[r] = lr[r] * al + rs;
            #pragma unroll
            for (int i = 0; i < 8; ++i) o[i][r] *= al;
        }
        // ---- P -> LDS (per-wave region, C-layout -> A-frag relayout) ----
        #pragma unroll
        for (int j = 0; j < 4; ++j)
            #pragma unroll
            for (int r = 0; r < 4; ++r)
                PsW[(quad * 4 + r) * 72 + j * 16 + col] = f2bf(pp[j][r]);
        // ---- PV: O[quad*4+r][dt*16+col] += P(16x64) * V(64x128) ----
        bf16x8 pa0 = *(const bf16x8*)&PsW[col * 72 + quad * 8];
        bf16x8 pa1 = *(const bf16x8*)&PsW[col * 72 + 32 + quad * 8];
        #pragma unroll
        for (int dt = 0; dt < 8; ++dt) {
            int row = dt * 16 + col;
            bf16x8 v0 = *(const bf16x8*)&Vs[p][row * 64 + ((quad * 8) ^ xk)];
            bf16x8 v1 = *(const bf16x8*)&Vs[p][row * 64 + ((32 + quad * 8) ^ xk)];
            __builtin_amdgcn_s_setprio(1);
            o[dt] = __builtin_amdgcn_mfma_f32_16x16x32_bf16(pa0, v0, o[dt], 0, 0, 0);
            o[dt] = __builtin_amdgcn_mfma_f32_16x16x32_bf16(pa1, v1, o[dt], 0, 0, 0);
            __builtin_amdgcn_s_setprio(0);
        }

        // ---- convert+write next K tile into Ks[p^1] (kvr arrived by now) ----
        if (pf) {
            #pragma unroll
            for (int i = 0; i < 8; ++i) {
                bf16x4 kb4;
                kb4[0] = f2bf(kvr[i].x); kb4[1] = f2bf(kvr[i].y);
                kb4[2] = f2bf(kvr[i].z); kb4[3] = f2bf(kvr[i].w);
                *(bf16x4*)&Ks[p ^ 1][(i * 8 + kr0) * 128 + kswz] = kb4;
            }
        }
        asm volatile("s_waitcnt vmcnt(0)" ::: "memory");  // V(t+1) landed
        __syncthreads();   // Ks writes visible; all waves done with buffers p
    }
    // ---- epilogue ----
    const int orow = (b * 2048 + s0 + w * 16) * 2048 + h * 128;
    #pragma unroll
    for (int r = 0; r < 4; ++r) {
        float inv = 1.f / lr[r];
        #pragma unroll
        for (int dt = 0; dt < 8; ++dt)
            Ot[orow + (quad * 4 + r) * 2048 + dt * 16 + col] = f2bf(o[dt][r] * inv);
    }
}

// ---------------------------------------------------------------------------
extern "C" void kernel_launch(void* const* d_in, const int* in_sizes, int n_in,
                              void* d_out, int out_size, void* d_ws, size_t ws_size,
                              hipStream_t stream) {
    const float* x  = (const float*)d_in[0];
    const float* pk = (const float*)d_in[1];
    const float* pv = (const float*)d_in[2];
    // d_in[3] = mask (unused: causal structure reproduced analytically)
    const float* wq = (const float*)d_in[4];
    const float* wk = (const float*)d_in[5];
    const float* wv = (const float*)d_in[6];
    const float* wo = (const float*)d_in[7];

    float* out  = (float*)d_out;                 // [2][2048][2048]
    float* kall = out + 8388608;                 // [2][4096][16][128]
    float* vall = out + 25165824;                // [2][4096][16][128]

    short* ws16 = (short*)d_ws;
    // 64 MiB workspace layout (overlapped lifetimes):
    short* xb  = ws16;                // [4096][2048] bf16; dead after gemm1 -> ot
    short* wqb = ws16 + 8388608;      // weights bf16; dead after gemm1
    short* wkb = ws16 + 12582912;
    short* wvb = ws16 + 16777216;
    short* wob = ws16 + 20971520;     // converted AFTER attn (region aliases Vtg)
    short* vtg = ws16 + 8388608;      // [2][16][128][4096] bf16; overlays weights
    short* qbf = ws16 + 25165824;     // [4096][2048] bf16
    short* ot  = xb;                  // alias: xb dead after gemm1

    // history -> kv cache, bit-exact fp32 (per batch: 4,194,304 floats = 16 MiB)
    hipMemcpyAsync(kall,           pk,           16777216u, hipMemcpyDeviceToDevice, stream);
    hipMemcpyAsync(kall + 8388608, pk + 4194304, 16777216u, hipMemcpyDeviceToDevice, stream);
    hipMemcpyAsync(vall,           pv,           16777216u, hipMemcpyDeviceToDevice, stream);
    hipMemcpyAsync(vall + 8388608, pv + 4194304, 16777216u, hipMemcpyDeviceToDevice, stream);

    // fp32 -> bf16 pre-pass for x and the QKV weights (wo converted later)
    cvt_kernel<<<1024, 256, 0, stream>>>(x,  xb,  2097152);
    cvt_kernel<<<512,  256, 0, stream>>>(wq, wqb, 1048576);
    cvt_kernel<<<512,  256, 0, stream>>>(wk, wkb, 1048576);
    cvt_kernel<<<512,  256, 0, stream>>>(wv, wvb, 1048576);

    // fused QKV projection: Q -> qbf (bf16), K/V chunk -> kall/vall (fp32)
    gemm_kernel<1><<<dim3(48, 32), 256, 0, stream>>>(xb, wqb, wkb, wvb,
                                                     qbf, kall, vall, nullptr);
    // V transpose+swizzle prep for MFMA attention (weights now dead)
    prep_v<<<dim3(64, 16, 2), 256, 0, stream>>>(vall, vtg);
    // MFMA flash attention (bh on x for XCD L2 locality; 64 q-rows/block;
    // double-buffered K/V pipeline)
    attn_mfma<<<dim3(32, 32), 256, 0, stream>>>(qbf, kall, vtg, ot);
    // wo conversion (vtg now dead) + output projection -> out (fp32)
    cvt_kernel<<<512, 256, 0, stream>>>(wo, wob, 1048576);
    gemm_kernel<0><<<dim3(16, 32), 256, 0, stream>>>(ot, wob, wob, wob,
                                                     nullptr, nullptr, nullptr, out);
}

// Round 5
// 834.751 us; speedup vs baseline: 1.3957x; 1.0282x over previous
//
#include <hip/hip_runtime.h>
#include <math.h>

typedef __attribute__((ext_vector_type(8))) short bf16x8;  // 8 bf16 = 4 VGPR
typedef __attribute__((ext_vector_type(4))) short bf16x4;  // 8 B
typedef __attribute__((ext_vector_type(4))) float f32x4;   // C/D frag

#define SSCL (0.08838834764831845f * 1.4426950408889634f)  // 1/sqrt(128) * log2(e)

__device__ __forceinline__ short f2bf(float f) {
    union { float f; unsigned u; } x; x.f = f;
    unsigned r = x.u + 0x7fffu + ((x.u >> 16) & 1u);
    return (short)(r >> 16);
}
__device__ __forceinline__ float bf2f(short s) {
    union { unsigned u; float f; } x;
    x.u = ((unsigned)(unsigned short)s) << 16;
    return x.f;
}

typedef const __attribute__((address_space(1))) unsigned int* gas_ptr;
typedef __attribute__((address_space(3))) unsigned int* las_ptr;
__device__ __forceinline__ void async_copy16(const void* g, void* l) {
    __builtin_amdgcn_global_load_lds((gas_ptr)g, (las_ptr)l, 16, 0, 0);
}

// ---------------------------------------------------------------------------
// fp32 -> bf16 conversion pre-pass (vectorized, grid-stride). n4 = nelem/4.
// ---------------------------------------------------------------------------
__global__ __launch_bounds__(256)
void cvt_kernel(const float* __restrict__ src, short* __restrict__ dst, int n4) {
    int i = blockIdx.x * 256 + threadIdx.x;
    const int stride = gridDim.x * 256;
    for (; i < n4; i += stride) {
        float4 v = ((const float4*)src)[i];
        bf16x4 o;
        o[0] = f2bf(v.x); o[1] = f2bf(v.y); o[2] = f2bf(v.z); o[3] = f2bf(v.w);
        ((bf16x4*)dst)[i] = o;
    }
}

// 3-source variant (weights): blockIdx.y selects src/dst pair.
__global__ __launch_bounds__(256)
void cvt3_kernel(const float* __restrict__ s0, const float* __restrict__ s1,
                 const float* __restrict__ s2, short* __restrict__ d0,
                 short* __restrict__ d1, short* __restrict__ d2, int n4) {
    const float* src = (blockIdx.y == 0) ? s0 : ((blockIdx.y == 1) ? s1 : s2);
    short* dst = (blockIdx.y == 0) ? d0 : ((blockIdx.y == 1) ? d1 : d2);
    int i = blockIdx.x * 256 + threadIdx.x;
    const int stride = gridDim.x * 256;
    for (; i < n4; i += stride) {
        float4 v = ((const float4*)src)[i];
        bf16x4 o;
        o[0] = f2bf(v.x); o[1] = f2bf(v.y); o[2] = f2bf(v.z); o[3] = f2bf(v.w);
        ((bf16x4*)dst)[i] = o;
    }
}

// ---------------------------------------------------------------------------
// NT GEMM (m97 pattern): D[m,n] = sum_k A[m,k]*B[n,k], bf16 in, fp32 acc.
// QKV=1: blockIdx.x in [0,48), sel=bx>>4: sel0 -> D16 (bf16, Q scratch),
//        sel1/2 -> Dk/Dv fp32 with kv-append row map m + ((m>>11)+1)*2048.
// QKV=0: blockIdx.x in [0,16), D = Df fp32 plain [4096,2048].
// ---------------------------------------------------------------------------
template<int QKV>
__global__ __launch_bounds__(256)
void gemm_kernel(const short* __restrict__ A,
                 const short* __restrict__ B0, const short* __restrict__ B1,
                 const short* __restrict__ B2,
                 short* __restrict__ D16, float* __restrict__ Dk,
                 float* __restrict__ Dv, float* __restrict__ Df) {
    __shared__ short As[128 * 64];
    __shared__ short Bs[128 * 64];
    const int tid = threadIdx.x, w = tid >> 6, ln = tid & 63;
    const int col = ln & 15, quad = ln >> 4;
    const int sel = QKV ? (blockIdx.x >> 4) : 0;
    const int tn = (blockIdx.x & 15) * 128;
    const int tm = blockIdx.y * 128;
    const short* B = (sel == 0) ? B0 : ((sel == 1) ? B1 : B2);

    const int wm = (w >> 1) * 64, wn = (w & 1) * 64;
    const int srow = ln >> 3, scol = (ln & 7) * 8;

    f32x4 acc[4][4];
    for (int i = 0; i < 4; ++i)
        for (int j = 0; j < 4; ++j)
            for (int e = 0; e < 4; ++e) acc[i][j][e] = 0.f;

    for (int k0 = 0; k0 < 2048; k0 += 64) {
        #pragma unroll
        for (int i = 0; i < 4; ++i) {
            int chunk = i * 4 + w;
            int row = chunk * 8 + srow;
            async_copy16(&A[(tm + row) * 2048 + k0 + scol], &As[chunk * 512]);
            async_copy16(&B[(tn + row) * 2048 + k0 + scol], &Bs[chunk * 512]);
        }
        asm volatile("s_waitcnt vmcnt(0)" ::: "memory");
        __syncthreads();
        #pragma unroll
        for (int kk = 0; kk < 2; ++kk) {
            bf16x8 af[4], bfr[4];
            #pragma unroll
            for (int i = 0; i < 4; ++i)
                af[i] = *(const bf16x8*)&As[(wm + i * 16 + col) * 64 + kk * 32 + quad * 8];
            #pragma unroll
            for (int j = 0; j < 4; ++j)
                bfr[j] = *(const bf16x8*)&Bs[(wn + j * 16 + col) * 64 + kk * 32 + quad * 8];
            __builtin_amdgcn_s_setprio(1);
            #pragma unroll
            for (int i = 0; i < 4; ++i)
                #pragma unroll
                for (int j = 0; j < 4; ++j)
                    acc[i][j] = __builtin_amdgcn_mfma_f32_16x16x32_bf16(af[i], bfr[j], acc[i][j], 0, 0, 0);
            __builtin_amdgcn_s_setprio(0);
        }
        __syncthreads();
    }
    // epilogue: C/D layout col = lane&15, row = quad*4 + reg
    for (int i = 0; i < 4; ++i)
        for (int j = 0; j < 4; ++j)
            for (int r = 0; r < 4; ++r) {
                int m = tm + wm + i * 16 + quad * 4 + r;
                int n = tn + wn + j * 16 + col;
                float v = acc[i][j][r];
                if (QKV) {
                    if (sel == 0) {
                        D16[m * 2048 + n] = f2bf(v);
                    } else {
                        int orow = m + ((m >> 11) + 1) * 2048;
                        float* D = (sel == 1) ? Dk : Dv;
                        D[orow * 2048 + n] = v;
                    }
                } else {
                    Df[m * 2048 + n] = v;
                }
            }
}

// ---------------------------------------------------------------------------
// K/V prep. One block per (64-key tile, h, b).
// K: fp32 kall [b][4096][16][128] -> bf16 Ktg [b][h][4096][128], column
//    XOR-swizzled within each row: Ktg[key][c ^ ((key&7)<<3)] = K[key][c],
//    so attention stages 64-key tiles linearly via global_load_lds and
//    ds_read_b128s them conflict-free (the fp32->bf16 convert happens ONCE
//    here instead of per-(q-tile) in the attention loop).
// V: fp32 vall -> bf16 transposed Vtg [b][h][128][4096], key-index swizzled
//    within each 64-key tile (kr ^ ((d&7)<<3)) via LDS transpose.
// ---------------------------------------------------------------------------
__global__ __launch_bounds__(256)
void prep_kv(const float* __restrict__ Kall, const float* __restrict__ Vall,
             short* __restrict__ Ktg, short* __restrict__ Vtg) {
    __shared__ short L[64 * 132];
    const int tid = threadIdx.x;
    const int k0 = blockIdx.x * 64;
    const int h = blockIdx.y, b = blockIdx.z;
    const float* Kb = Kall + ((size_t)(b * 4096) * 16 + h) * 128;
    const float* Vb = Vall + ((size_t)(b * 4096) * 16 + h) * 128;
    short* Ko = Ktg + ((size_t)(b * 16 + h) * 4096) * 128;
    short* Vo = Vtg + ((size_t)(b * 16 + h) * 128) * 4096;
    // ---- K: direct convert + in-row swizzle ----
    #pragma unroll
    for (int i = 0; i < 8; ++i) {
        int idx = i * 256 + tid;
        int kr = idx >> 5, c4 = (idx & 31) * 4;
        float4 v = *(const float4*)&Kb[(size_t)(k0 + kr) * 2048 + c4];
        bf16x4 o4;
        o4[0] = f2bf(v.x); o4[1] = f2bf(v.y); o4[2] = f2bf(v.z); o4[3] = f2bf(v.w);
        *(bf16x4*)&Ko[(size_t)(k0 + kr) * 128 + (c4 ^ ((kr & 7) << 3))] = o4;
    }
    // ---- V: LDS transpose + swizzle ----
    #pragma unroll
    for (int i = 0; i < 8; ++i) {
        int idx = i * 256 + tid;
        int r = idx >> 5, c4 = (idx & 31) * 4;
        float4 v = *(const float4*)&Vb[(size_t)(k0 + r) * 2048 + c4];
        bf16x4 o4;
        o4[0] = f2bf(v.x); o4[1] = f2bf(v.y); o4[2] = f2bf(v.z); o4[3] = f2bf(v.w);
        *(bf16x4*)&L[r * 132 + c4] = o4;
    }
    __syncthreads();
    #pragma unroll
    for (int i = 0; i < 8; ++i) {
        int idx = i * 256 + tid;
        int d = idx >> 4, kc4 = (idx & 15) * 4;
        bf16x4 o4;
        o4[0] = L[(kc4 + 0) * 132 + d];
        o4[1] = L[(kc4 + 1) * 132 + d];
        o4[2] = L[(kc4 + 2) * 132 + d];
        o4[3] = L[(kc4 + 3) * 132 + d];
        *(bf16x4*)&Vo[(size_t)d * 4096 + k0 + (kc4 ^ ((d & 7) << 3))] = o4;
    }
}

// ---------------------------------------------------------------------------
// MFMA flash attention, double-buffered all-DMA pipeline. grid (bh=32,
// qtile=32), block 256 = 4 waves; 64 q-rows/block (wave w: rows s0+w*16..+15).
// bh on grid.x => XCD = bh%8 for every qtile => K/V L2 locality.
// Both K and V tiles are pre-converted bf16, pre-swizzled in global, staged
// via global_load_lds: per tile t, issue 8 async copies (t+1 -> bufs p^1)
// BEFORE compute on bufs p; one vmcnt(0)+barrier per tile. Zero VALU spent
// on staging.
// ---------------------------------------------------------------------------
__global__ __launch_bounds__(256)
void attn_mfma(const short* __restrict__ Q, const short* __restrict__ Ktg,
               const short* __restrict__ Vtg, short* __restrict__ Ot) {
    __shared__ short Ks[2][64 * 128];
    __shared__ short Vs[2][128 * 64];
    __shared__ short Ps[4 * 16 * 72];
    const int tid = threadIdx.x, w = tid >> 6, ln = tid & 63;
    const int col = ln & 15, quad = ln >> 4;
    const int bh = blockIdx.x;
    const int b = bh >> 4, h = bh & 15;
    const int s0 = blockIdx.y * 64;
    const int xk = (col & 7) << 3;   // fragment-read swizzle term

    // Q fragments (one-time)
    bf16x8 qf[4];
    {
        const int qr = (b * 2048 + s0 + w * 16 + col) * 2048 + h * 128;
        #pragma unroll
        for (int ks = 0; ks < 4; ++ks)
            qf[ks] = *(const bf16x8*)&Q[qr + ks * 32 + quad * 8];
    }
    f32x4 o[8];
    #pragma unroll
    for (int i = 0; i < 8; ++i)
        for (int e = 0; e < 4; ++e) o[i][e] = 0.f;
    float mr[4] = {-1e30f, -1e30f, -1e30f, -1e30f};
    float lr[4] = {0.f, 0.f, 0.f, 0.f};

    const short* Kb = Ktg + ((size_t)(b * 16 + h) * 4096) * 128;
    const short* Vb = Vtg + ((size_t)(b * 16 + h) * 128) * 4096;
    short* PsW = &Ps[w * 1152];

    // per-thread staging bases (hoisted)
    const int kr4 = ln >> 4;               // K: row-in-4 within chunk
    const int kc8 = (ln & 15) * 8;         // K: col offset (8 shorts)
    const int vd = (ln >> 3);              // V: d sub-row within chunk
    const int vkofs = (ln & 7) * 8;        // V: key offset within tile

    const int ntiles = 33 + blockIdx.y;    // (2048 + s0 + 64)/64

    // ---- prologue: stage tile 0 into buffers 0 ----
    #pragma unroll
    for (int i = 0; i < 4; ++i) {
        int ch = i * 4 + w;
        async_copy16(&Kb[(size_t)(ch * 4 + kr4) * 128 + kc8], &Ks[0][ch * 512]);
        async_copy16(&Vb[(size_t)(ch * 8 + vd) * 4096 + vkofs], &Vs[0][ch * 512]);
    }
    asm volatile("s_waitcnt vmcnt(0)" ::: "memory");
    __syncthreads();

    for (int t = 0; t < ntiles; ++t) {
        const int p = t & 1;
        const int k0 = t * 64;
        const bool pf = (t + 1 < ntiles);   // block-uniform prefetch guard

        // ---- issue next-tile DMA (K,V -> bufs p^1) ----
        if (pf) {
            const int k0n = k0 + 64;
            #pragma unroll
            for (int i = 0; i < 4; ++i) {
                int ch = i * 4 + w;
                async_copy16(&Kb[(size_t)(k0n + ch * 4 + kr4) * 128 + kc8],
                             &Ks[p ^ 1][ch * 512]);
                async_copy16(&Vb[(size_t)(ch * 8 + vd) * 4096 + k0n + vkofs],
                             &Vs[p ^ 1][ch * 512]);
            }
        }

        // ---- QK^T: S[quad*4+r][j*16+col] ----
        f32x4 s4[4];
        #pragma unroll
        for (int j = 0; j < 4; ++j)
            for (int e = 0; e < 4; ++e) s4[j][e] = 0.f;
        #pragma unroll
        for (int ks = 0; ks < 4; ++ks) {
            const int dofs = (ks * 32 + quad * 8) ^ xk;
            bf16x8 kf[4];
            #pragma unroll
            for (int j = 0; j < 4; ++j)
                kf[j] = *(const bf16x8*)&Ks[p][(j * 16 + col) * 128 + dofs];
            __builtin_amdgcn_s_setprio(1);
            #pragma unroll
            for (int j = 0; j < 4; ++j)
                s4[j] = __builtin_amdgcn_mfma_f32_16x16x32_bf16(qf[ks], kf[j], s4[j], 0, 0, 0);
            __builtin_amdgcn_s_setprio(0);
        }

        // ---- online softmax (scaled base-2 domain) ----
        const bool full = (k0 + 63 <= 2048 + s0 + w * 16);  // wave-uniform
        float pp[4][4];
        if (full) {
            #pragma unroll
            for (int j = 0; j < 4; ++j)
                #pragma unroll
                for (int r = 0; r < 4; ++r) pp[j][r] = s4[j][r] * SSCL;
        } else {
            #pragma unroll
            for (int j = 0; j < 4; ++j) {
                int kp = k0 + j * 16 + col;
                #pragma unroll
                for (int r = 0; r < 4; ++r) {
                    int qp = 2048 + s0 + w * 16 + quad * 4 + r;
                    pp[j][r] = (kp <= qp) ? s4[j][r] * SSCL : -1e30f;
                }
            }
        }
        #pragma unroll
        for (int r = 0; r < 4; ++r) {
            float mx = fmaxf(fmaxf(pp[0][r], pp[1][r]), fmaxf(pp[2][r], pp[3][r]));
            mx = fmaxf(mx, __shfl_xor(mx, 1));
            mx = fmaxf(mx, __shfl_xor(mx, 2));
            mx = fmaxf(mx, __shfl_xor(mx, 4));
            mx = fmaxf(mx, __shfl_xor(mx, 8));
            float mn = fmaxf(mr[r], mx);
            float al = exp2f(mr[r] - mn);
            mr[r] = mn;
            float rs = 0.f;
            #pragma unroll
            for (int j = 0; j < 4; ++j) { pp[j][r] = exp2f(pp[j][r] - mn); rs += pp[j][r]; }
            rs += __shfl_xor(rs, 1);
            rs += __shfl_xor(rs, 2);
            rs += __shfl_xor(rs, 4);
            rs += __shfl_xor(rs, 8);
            lr[r] = lr[r] * al + rs;
            #pragma unroll
            for (int i = 0; i < 8; ++i) o[i][r] *= al;
        }
        // ---- P -> LDS (per-wave region, C-layout -> A-frag relayout) ----
        #pragma unroll
        for (int j = 0; j < 4; ++j)
            #pragma unroll
            for (int r = 0; r < 4; ++r)
                PsW[(quad * 4 + r) * 72 + j * 16 + col] = f2bf(pp[j][r]);
        // ---- PV: O[quad*4+r][dt*16+col] += P(16x64) * V(64x128) ----
        bf16x8 pa0 = *(const bf16x8*)&PsW[col * 72 + quad * 8];
        bf16x8 pa1 = *(const bf16x8*)&PsW[col * 72 + 32 + quad * 8];
        #pragma unroll
        for (int dt = 0; dt < 8; ++dt) {
            int row = dt * 16 + col;
            bf16x8 v0 = *(const bf16x8*)&Vs[p][row * 64 + ((quad * 8) ^ xk)];
            bf16x8 v1 = *(const bf16x8*)&Vs[p][row * 64 + ((32 + quad * 8) ^ xk)];
            __builtin_amdgcn_s_setprio(1);
            o[dt] = __builtin_amdgcn_mfma_f32_16x16x32_bf16(pa0, v0, o[dt], 0, 0, 0);
            o[dt] = __builtin_amdgcn_mfma_f32_16x16x32_bf16(pa1, v1, o[dt], 0, 0, 0);
            __builtin_amdgcn_s_setprio(0);
        }

        asm volatile("s_waitcnt vmcnt(0)" ::: "memory");  // t+1 DMA landed
        __syncthreads();   // all waves done with bufs p; p^1 ready
    }
    // ---- epilogue ----
    const int orow = (b * 2048 + s0 + w * 16) * 2048 + h * 128;
    #pragma unroll
    for (int r = 0; r < 4; ++r) {
        float inv = 1.f / lr[r];
        #pragma unroll
        for (int dt = 0; dt < 8; ++dt)
            Ot[orow + (quad * 4 + r) * 2048 + dt * 16 + col] = f2bf(o[dt][r] * inv);
    }
}

// ---------------------------------------------------------------------------
extern "C" void kernel_launch(void* const* d_in, const int* in_sizes, int n_in,
                              void* d_out, int out_size, void* d_ws, size_t ws_size,
                              hipStream_t stream) {
    const float* x  = (const float*)d_in[0];
    const float* pk = (const float*)d_in[1];
    const float* pv = (const float*)d_in[2];
    // d_in[3] = mask (unused: causal structure reproduced analytically)
    const float* wq = (const float*)d_in[4];
    const float* wk = (const float*)d_in[5];
    const float* wv = (const float*)d_in[6];
    const float* wo = (const float*)d_in[7];

    float* out  = (float*)d_out;                 // [2][2048][2048]
    float* kall = out + 8388608;                 // [2][4096][16][128]
    float* vall = out + 25165824;                // [2][4096][16][128]

    short* ws16 = (short*)d_ws;
    // 64 MiB workspace layout (overlapped lifetimes):
    short* xb  = ws16;                // [4096][2048] bf16; dead after gemm1 -> ot
    short* wqb = ws16 + 8388608;      // weights bf16; dead after gemm1
    short* wkb = ws16 + 12582912;
    short* wvb = ws16 + 16777216;
    short* wob = ws16 + 20971520;     // converted AFTER attn (region aliases Vtg)
    short* vtg = ws16 + 8388608;      // [2][16][128][4096] bf16; overlays weights
    short* qbf = ws16 + 25165824;     // [4096][2048] bf16
    short* ot  = xb;                  // alias: xb dead after gemm1
    short* ktg = (short*)out;         // [2][16][4096][128] bf16 = 32 MiB scratch
                                      // in out[0..8388608) floats; dead before
                                      // gemm0 overwrites that region.

    // history -> kv cache, bit-exact fp32 (per batch: 4,194,304 floats = 16 MiB)
    hipMemcpyAsync(kall,           pk,           16777216u, hipMemcpyDeviceToDevice, stream);
    hipMemcpyAsync(kall + 8388608, pk + 4194304, 16777216u, hipMemcpyDeviceToDevice, stream);
    hipMemcpyAsync(vall,           pv,           16777216u, hipMemcpyDeviceToDevice, stream);
    hipMemcpyAsync(vall + 8388608, pv + 4194304, 16777216u, hipMemcpyDeviceToDevice, stream);

    // fp32 -> bf16 pre-pass for x and the QKV weights (wo converted later)
    cvt_kernel<<<1024, 256, 0, stream>>>(x, xb, 2097152);
    cvt3_kernel<<<dim3(512, 3), 256, 0, stream>>>(wq, wk, wv, wqb, wkb, wvb, 1048576);

    // fused QKV projection: Q -> qbf (bf16), K/V chunk -> kall/vall (fp32)
    gemm_kernel<1><<<dim3(48, 32), 256, 0, stream>>>(xb, wqb, wkb, wvb,
                                                     qbf, kall, vall, nullptr);
    // K convert+swizzle and V transpose+swizzle prep (weights now dead)
    prep_kv<<<dim3(64, 16, 2), 256, 0, stream>>>(kall, vall, ktg, vtg);
    // MFMA flash attention (bh on x for XCD L2 locality; all-DMA staging)
    attn_mfma<<<dim3(32, 32), 256, 0, stream>>>(qbf, ktg, vtg, ot);
    // wo conversion (vtg now dead) + output projection -> out (fp32)
    cvt_kernel<<<512, 256, 0, stream>>>(wo, wob, 1048576);
    gemm_kernel<0><<<dim3(16, 32), 256, 0, stream>>>(ot, wob, wob, wob,
                                                     nullptr, nullptr, nullptr, out);
}

// Round 6
// 764.141 us; speedup vs baseline: 1.5246x; 1.0924x over previous
//
#include <hip/hip_runtime.h>
#include <math.h>

typedef __attribute__((ext_vector_type(8))) short bf16x8;  // 8 bf16 = 4 VGPR
typedef __attribute__((ext_vector_type(4))) short bf16x4;  // 8 B
typedef __attribute__((ext_vector_type(4))) float f32x4;   // C/D frag

#define SSCL (0.08838834764831845f * 1.4426950408889634f)  // 1/sqrt(128) * log2(e)

__device__ __forceinline__ short f2bf(float f) {
    union { float f; unsigned u; } x; x.f = f;
    unsigned r = x.u + 0x7fffu + ((x.u >> 16) & 1u);
    return (short)(r >> 16);
}

typedef const __attribute__((address_space(1))) unsigned int* gas_ptr;
typedef __attribute__((address_space(3))) unsigned int* las_ptr;
__device__ __forceinline__ void async_copy16(const void* g, void* l) {
    __builtin_amdgcn_global_load_lds((gas_ptr)g, (las_ptr)l, 16, 0, 0);
}

// ---------------------------------------------------------------------------
// fp32 -> bf16 conversion pre-pass (vectorized, grid-stride). n4 = nelem/4.
// ---------------------------------------------------------------------------
__global__ __launch_bounds__(256)
void cvt_kernel(const float* __restrict__ src, short* __restrict__ dst, int n4) {
    int i = blockIdx.x * 256 + threadIdx.x;
    const int stride = gridDim.x * 256;
    for (; i < n4; i += stride) {
        float4 v = ((const float4*)src)[i];
        bf16x4 o;
        o[0] = f2bf(v.x); o[1] = f2bf(v.y); o[2] = f2bf(v.z); o[3] = f2bf(v.w);
        ((bf16x4*)dst)[i] = o;
    }
}

// 3-source variant (weights): blockIdx.y selects src/dst pair.
__global__ __launch_bounds__(256)
void cvt3_kernel(const float* __restrict__ s0, const float* __restrict__ s1,
                 const float* __restrict__ s2, short* __restrict__ d0,
                 short* __restrict__ d1, short* __restrict__ d2, int n4) {
    const float* src = (blockIdx.y == 0) ? s0 : ((blockIdx.y == 1) ? s1 : s2);
    short* dst = (blockIdx.y == 0) ? d0 : ((blockIdx.y == 1) ? d1 : d2);
    int i = blockIdx.x * 256 + threadIdx.x;
    const int stride = gridDim.x * 256;
    for (; i < n4; i += stride) {
        float4 v = ((const float4*)src)[i];
        bf16x4 o;
        o[0] = f2bf(v.x); o[1] = f2bf(v.y); o[2] = f2bf(v.z); o[3] = f2bf(v.w);
        ((bf16x4*)dst)[i] = o;
    }
}

// ---------------------------------------------------------------------------
// NT GEMM (m97 pattern): D[m,n] = sum_k A[m,k]*B[n,k], bf16 in, fp32 acc.
// QKV=1: blockIdx.x in [0,48), sel=bx>>4: sel0 -> D16 (bf16 Q, PRE-SCALED by
//        SSCL so attention skips the per-score multiply),
//        sel1/2 -> Dk/Dv fp32 with kv-append row map m + ((m>>11)+1)*2048.
// QKV=0: blockIdx.x in [0,16), D = Df fp32 plain [4096,2048].
// ---------------------------------------------------------------------------
template<int QKV>
__global__ __launch_bounds__(256)
void gemm_kernel(const short* __restrict__ A,
                 const short* __restrict__ B0, const short* __restrict__ B1,
                 const short* __restrict__ B2,
                 short* __restrict__ D16, float* __restrict__ Dk,
                 float* __restrict__ Dv, float* __restrict__ Df) {
    __shared__ short As[128 * 64];
    __shared__ short Bs[128 * 64];
    const int tid = threadIdx.x, w = tid >> 6, ln = tid & 63;
    const int col = ln & 15, quad = ln >> 4;
    const int sel = QKV ? (blockIdx.x >> 4) : 0;
    const int tn = (blockIdx.x & 15) * 128;
    const int tm = blockIdx.y * 128;
    const short* B = (sel == 0) ? B0 : ((sel == 1) ? B1 : B2);

    const int wm = (w >> 1) * 64, wn = (w & 1) * 64;
    const int srow = ln >> 3, scol = (ln & 7) * 8;

    f32x4 acc[4][4];
    for (int i = 0; i < 4; ++i)
        for (int j = 0; j < 4; ++j)
            for (int e = 0; e < 4; ++e) acc[i][j][e] = 0.f;

    for (int k0 = 0; k0 < 2048; k0 += 64) {
        #pragma unroll
        for (int i = 0; i < 4; ++i) {
            int chunk = i * 4 + w;
            int row = chunk * 8 + srow;
            async_copy16(&A[(tm + row) * 2048 + k0 + scol], &As[chunk * 512]);
            async_copy16(&B[(tn + row) * 2048 + k0 + scol], &Bs[chunk * 512]);
        }
        asm volatile("s_waitcnt vmcnt(0)" ::: "memory");
        __syncthreads();
        #pragma unroll
        for (int kk = 0; kk < 2; ++kk) {
            bf16x8 af[4], bfr[4];
            #pragma unroll
            for (int i = 0; i < 4; ++i)
                af[i] = *(const bf16x8*)&As[(wm + i * 16 + col) * 64 + kk * 32 + quad * 8];
            #pragma unroll
            for (int j = 0; j < 4; ++j)
                bfr[j] = *(const bf16x8*)&Bs[(wn + j * 16 + col) * 64 + kk * 32 + quad * 8];
            __builtin_amdgcn_s_setprio(1);
            #pragma unroll
            for (int i = 0; i < 4; ++i)
                #pragma unroll
                for (int j = 0; j < 4; ++j)
                    acc[i][j] = __builtin_amdgcn_mfma_f32_16x16x32_bf16(af[i], bfr[j], acc[i][j], 0, 0, 0);
            __builtin_amdgcn_s_setprio(0);
        }
        __syncthreads();
    }
    // epilogue: C/D layout col = lane&15, row = quad*4 + reg
    for (int i = 0; i < 4; ++i)
        for (int j = 0; j < 4; ++j)
            for (int r = 0; r < 4; ++r) {
                int m = tm + wm + i * 16 + quad * 4 + r;
                int n = tn + wn + j * 16 + col;
                float v = acc[i][j][r];
                if (QKV) {
                    if (sel == 0) {
                        D16[m * 2048 + n] = f2bf(v * SSCL);
                    } else {
                        int orow = m + ((m >> 11) + 1) * 2048;
                        float* D = (sel == 1) ? Dk : Dv;
                        D[orow * 2048 + n] = v;
                    }
                } else {
                    Df[m * 2048 + n] = v;
                }
            }
}

// ---------------------------------------------------------------------------
// K/V prep. One block per (64-key tile, h, b).
// K: fp32 kall [b][4096][16][128] -> bf16 Ktg [b][h][4096][128], column
//    XOR-swizzled within each row: Ktg[key][c ^ ((key&7)<<3)] = K[key][c].
// V: fp32 vall -> bf16 transposed Vtg [b][h][128][4096], key-index swizzled
//    within each 64-key tile (kr ^ ((d&7)<<3)) via LDS transpose.
// ---------------------------------------------------------------------------
__global__ __launch_bounds__(256)
void prep_kv(const float* __restrict__ Kall, const float* __restrict__ Vall,
             short* __restrict__ Ktg, short* __restrict__ Vtg) {
    __shared__ short L[64 * 132];
    const int tid = threadIdx.x;
    const int k0 = blockIdx.x * 64;
    const int h = blockIdx.y, b = blockIdx.z;
    const float* Kb = Kall + ((size_t)(b * 4096) * 16 + h) * 128;
    const float* Vb = Vall + ((size_t)(b * 4096) * 16 + h) * 128;
    short* Ko = Ktg + ((size_t)(b * 16 + h) * 4096) * 128;
    short* Vo = Vtg + ((size_t)(b * 16 + h) * 128) * 4096;
    // ---- K: direct convert + in-row swizzle ----
    #pragma unroll
    for (int i = 0; i < 8; ++i) {
        int idx = i * 256 + tid;
        int kr = idx >> 5, c4 = (idx & 31) * 4;
        float4 v = *(const float4*)&Kb[(size_t)(k0 + kr) * 2048 + c4];
        bf16x4 o4;
        o4[0] = f2bf(v.x); o4[1] = f2bf(v.y); o4[2] = f2bf(v.z); o4[3] = f2bf(v.w);
        *(bf16x4*)&Ko[(size_t)(k0 + kr) * 128 + (c4 ^ ((kr & 7) << 3))] = o4;
    }
    // ---- V: LDS transpose + swizzle ----
    #pragma unroll
    for (int i = 0; i < 8; ++i) {
        int idx = i * 256 + tid;
        int r = idx >> 5, c4 = (idx & 31) * 4;
        float4 v = *(const float4*)&Vb[(size_t)(k0 + r) * 2048 + c4];
        bf16x4 o4;
        o4[0] = f2bf(v.x); o4[1] = f2bf(v.y); o4[2] = f2bf(v.z); o4[3] = f2bf(v.w);
        *(bf16x4*)&L[r * 132 + c4] = o4;
    }
    __syncthreads();
    #pragma unroll
    for (int i = 0; i < 8; ++i) {
        int idx = i * 256 + tid;
        int d = idx >> 4, kc4 = (idx & 15) * 4;
        bf16x4 o4;
        o4[0] = L[(kc4 + 0) * 132 + d];
        o4[1] = L[(kc4 + 1) * 132 + d];
        o4[2] = L[(kc4 + 2) * 132 + d];
        o4[3] = L[(kc4 + 3) * 132 + d];
        *(bf16x4*)&Vo[(size_t)d * 4096 + k0 + (kc4 ^ ((d & 7) << 3))] = o4;
    }
}

// ---------------------------------------------------------------------------
// MFMA flash attention, double-buffered all-DMA pipeline + SWAPPED QK^T.
// grid (bh=32, qtile=32), block 256 = 4 waves; 64 q-rows/block.
// QK^T computed as mfma(K, Q) so S^T has qrow = lane&15: each lane owns 16
// scores (keys j*16+quad*4+r) of ONE q-row. Row max/sum = 15 in-reg ops +
// 2 shfl_xor (cross-quad) instead of 4x 4-deep shuffle chains; softmax
// state (m,l) is scalar per lane. Exact defer-rescale: when __all(mx<=m)
// the rescale is identity (al==1) and is skipped bit-exactly.
// P-store: 4x ds_write_b64 (r-consecutive keys) into Ps[qrow][key] -- the
// PV read side (pa = Ps[col*72 + quad*8...]) is unchanged from round 5.
// ---------------------------------------------------------------------------
__global__ __launch_bounds__(256)
void attn_mfma(const short* __restrict__ Q, const short* __restrict__ Ktg,
               const short* __restrict__ Vtg, short* __restrict__ Ot) {
    __shared__ short Ks[2][64 * 128];
    __shared__ short Vs[2][128 * 64];
    __shared__ short Ps[4 * 16 * 72];
    const int tid = threadIdx.x, w = tid >> 6, ln = tid & 63;
    const int col = ln & 15, quad = ln >> 4;
    const int bh = blockIdx.x;
    const int b = bh >> 4, h = bh & 15;
    const int s0 = blockIdx.y * 64;
    const int xk = (col & 7) << 3;   // fragment-read swizzle term

    // Q fragments (one-time); Q is pre-scaled by SSCL in gemm1's epilogue
    bf16x8 qf[4];
    {
        const int qr = (b * 2048 + s0 + w * 16 + col) * 2048 + h * 128;
        #pragma unroll
        for (int ks = 0; ks < 4; ++ks)
            qf[ks] = *(const bf16x8*)&Q[qr + ks * 32 + quad * 8];
    }
    f32x4 o[8];
    #pragma unroll
    for (int i = 0; i < 8; ++i)
        for (int e = 0; e < 4; ++e) o[i][e] = 0.f;
    float m = -1e30f, l = 0.f;      // per-lane state for qrow = col

    const short* Kb = Ktg + ((size_t)(b * 16 + h) * 4096) * 128;
    const short* Vb = Vtg + ((size_t)(b * 16 + h) * 128) * 4096;
    short* PsW = &Ps[w * 1152];

    // per-thread staging bases (hoisted)
    const int kr4 = ln >> 4;               // K: row-in-4 within chunk
    const int kc8 = (ln & 15) * 8;         // K: col offset (8 shorts)
    const int vd = (ln >> 3);              // V: d sub-row within chunk
    const int vkofs = (ln & 7) * 8;        // V: key offset within tile

    const int ntiles = 33 + blockIdx.y;    // (2048 + s0 + 64)/64
    const int qp = 2048 + s0 + w * 16 + col;   // my q position (causal bound)

    // ---- prologue: stage tile 0 into buffers 0 ----
    #pragma unroll
    for (int i = 0; i < 4; ++i) {
        int ch = i * 4 + w;
        async_copy16(&Kb[(size_t)(ch * 4 + kr4) * 128 + kc8], &Ks[0][ch * 512]);
        async_copy16(&Vb[(size_t)(ch * 8 + vd) * 4096 + vkofs], &Vs[0][ch * 512]);
    }
    asm volatile("s_waitcnt vmcnt(0)" ::: "memory");
    __syncthreads();

    for (int t = 0; t < ntiles; ++t) {
        const int p = t & 1;
        const int k0 = t * 64;
        const bool pf = (t + 1 < ntiles);   // block-uniform prefetch guard

        // ---- issue next-tile DMA (K,V -> bufs p^1) ----
        if (pf) {
            const int k0n = k0 + 64;
            #pragma unroll
            for (int i = 0; i < 4; ++i) {
                int ch = i * 4 + w;
                async_copy16(&Kb[(size_t)(k0n + ch * 4 + kr4) * 128 + kc8],
                             &Ks[p ^ 1][ch * 512]);
                async_copy16(&Vb[(size_t)(ch * 8 + vd) * 4096 + k0n + vkofs],
                             &Vs[p ^ 1][ch * 512]);
            }
        }

        // ---- swapped QK^T: S^T[key = j*16+quad*4+r][qrow = col] ----
        f32x4 s4[4];
        #pragma unroll
        for (int j = 0; j < 4; ++j)
            for (int e = 0; e < 4; ++e) s4[j][e] = 0.f;
        #pragma unroll
        for (int ks = 0; ks < 4; ++ks) {
            const int dofs = (ks * 32 + quad * 8) ^ xk;
            bf16x8 kf[4];
            #pragma unroll
            for (int j = 0; j < 4; ++j)
                kf[j] = *(const bf16x8*)&Ks[p][(j * 16 + col) * 128 + dofs];
            __builtin_amdgcn_s_setprio(1);
            #pragma unroll
            for (int j = 0; j < 4; ++j)
                s4[j] = __builtin_amdgcn_mfma_f32_16x16x32_bf16(kf[j], qf[ks], s4[j], 0, 0, 0);
            __builtin_amdgcn_s_setprio(0);
        }

        // ---- lane-local online softmax (base-2 domain; Q pre-scaled) ----
        const bool full = (k0 + 63 <= 2048 + s0 + w * 16);  // wave-uniform
        float pp[4][4];
        if (full) {
            #pragma unroll
            for (int j = 0; j < 4; ++j)
                #pragma unroll
                for (int r = 0; r < 4; ++r) pp[j][r] = s4[j][r];
        } else {
            #pragma unroll
            for (int j = 0; j < 4; ++j) {
                #pragma unroll
                for (int r = 0; r < 4; ++r) {
                    int kp = k0 + j * 16 + quad * 4 + r;
                    pp[j][r] = (kp <= qp) ? s4[j][r] : -1e30f;
                }
            }
        }
        // row max: 16 in-reg values + cross-quad butterfly
        float mx = pp[0][0];
        #pragma unroll
        for (int j = 0; j < 4; ++j)
            #pragma unroll
            for (int r = 0; r < 4; ++r) mx = fmaxf(mx, pp[j][r]);
        mx = fmaxf(mx, __shfl_xor(mx, 16));
        mx = fmaxf(mx, __shfl_xor(mx, 32));

        if (__all(mx <= m)) {
            // exact defer: al == 1, skip rescale entirely
            float rs = 0.f;
            #pragma unroll
            for (int j = 0; j < 4; ++j)
                #pragma unroll
                for (int r = 0; r < 4; ++r) { pp[j][r] = exp2f(pp[j][r] - m); rs += pp[j][r]; }
            rs += __shfl_xor(rs, 16);
            rs += __shfl_xor(rs, 32);
            l += rs;
        } else {
            float mn = fmaxf(m, mx);
            float al = exp2f(m - mn);
            m = mn;
            float rs = 0.f;
            #pragma unroll
            for (int j = 0; j < 4; ++j)
                #pragma unroll
                for (int r = 0; r < 4; ++r) { pp[j][r] = exp2f(pp[j][r] - mn); rs += pp[j][r]; }
            rs += __shfl_xor(rs, 16);
            rs += __shfl_xor(rs, 32);
            l = l * al + rs;
            // broadcast al from lane (qrow=col) space to C-row (quad*4+r) space
            #pragma unroll
            for (int r = 0; r < 4; ++r) {
                float alr = __shfl(al, quad * 4 + r);
                #pragma unroll
                for (int i = 0; i < 8; ++i) o[i][r] *= alr;
            }
        }

        // ---- P -> LDS: Ps[qrow=col][key], 4x b64 (r-consecutive keys) ----
        #pragma unroll
        for (int j = 0; j < 4; ++j) {
            bf16x4 pb;
            pb[0] = f2bf(pp[j][0]); pb[1] = f2bf(pp[j][1]);
            pb[2] = f2bf(pp[j][2]); pb[3] = f2bf(pp[j][3]);
            *(bf16x4*)&PsW[col * 72 + j * 16 + quad * 4] = pb;
        }
        // ---- PV: O[qrow=quad*4+r][dt*16+col] += P(16x64) * V(64x128) ----
        bf16x8 pa0 = *(const bf16x8*)&PsW[col * 72 + quad * 8];
        bf16x8 pa1 = *(const bf16x8*)&PsW[col * 72 + 32 + quad * 8];
        #pragma unroll
        for (int dt = 0; dt < 8; ++dt) {
            int row = dt * 16 + col;
            bf16x8 v0 = *(const bf16x8*)&Vs[p][row * 64 + ((quad * 8) ^ xk)];
            bf16x8 v1 = *(const bf16x8*)&Vs[p][row * 64 + ((32 + quad * 8) ^ xk)];
            __builtin_amdgcn_s_setprio(1);
            o[dt] = __builtin_amdgcn_mfma_f32_16x16x32_bf16(pa0, v0, o[dt], 0, 0, 0);
            o[dt] = __builtin_amdgcn_mfma_f32_16x16x32_bf16(pa1, v1, o[dt], 0, 0, 0);
            __builtin_amdgcn_s_setprio(0);
        }

        asm volatile("s_waitcnt vmcnt(0)" ::: "memory");  // t+1 DMA landed
        __syncthreads();   // all waves done with bufs p; p^1 ready
    }
    // ---- epilogue: l lives at lane (qrow=col); O rows are quad*4+r ----
    const int orow = (b * 2048 + s0 + w * 16) * 2048 + h * 128;
    #pragma unroll
    for (int r = 0; r < 4; ++r) {
        float inv = 1.f / __shfl(l, quad * 4 + r);
        #pragma unroll
        for (int dt = 0; dt < 8; ++dt)
            Ot[orow + (quad * 4 + r) * 2048 + dt * 16 + col] = f2bf(o[dt][r] * inv);
    }
}

// ---------------------------------------------------------------------------
extern "C" void kernel_launch(void* const* d_in, const int* in_sizes, int n_in,
                              void* d_out, int out_size, void* d_ws, size_t ws_size,
                              hipStream_t stream) {
    const float* x  = (const float*)d_in[0];
    const float* pk = (const float*)d_in[1];
    const float* pv = (const float*)d_in[2];
    // d_in[3] = mask (unused: causal structure reproduced analytically)
    const float* wq = (const float*)d_in[4];
    const float* wk = (const float*)d_in[5];
    const float* wv = (const float*)d_in[6];
    const float* wo = (const float*)d_in[7];

    float* out  = (float*)d_out;                 // [2][2048][2048]
    float* kall = out + 8388608;                 // [2][4096][16][128]
    float* vall = out + 25165824;                // [2][4096][16][128]

    short* ws16 = (short*)d_ws;
    // 64 MiB workspace layout (overlapped lifetimes):
    short* xb  = ws16;                // [4096][2048] bf16; dead after gemm1 -> ot
    short* wqb = ws16 + 8388608;      // weights bf16; dead after gemm1
    short* wkb = ws16 + 12582912;
    short* wvb = ws16 + 16777216;
    short* wob = ws16 + 20971520;     // converted AFTER attn (region aliases Vtg)
    short* vtg = ws16 + 8388608;      // [2][16][128][4096] bf16; overlays weights
    short* qbf = ws16 + 25165824;     // [4096][2048] bf16
    short* ot  = xb;                  // alias: xb dead after gemm1
    short* ktg = (short*)out;         // [2][16][4096][128] bf16 = 32 MiB scratch
                                      // in out[0..8388608) floats; dead before
                                      // gemm0 overwrites that region.

    // history -> kv cache, bit-exact fp32 (per batch: 4,194,304 floats = 16 MiB)
    hipMemcpyAsync(kall,           pk,           16777216u, hipMemcpyDeviceToDevice, stream);
    hipMemcpyAsync(kall + 8388608, pk + 4194304, 16777216u, hipMemcpyDeviceToDevice, stream);
    hipMemcpyAsync(vall,           pv,           16777216u, hipMemcpyDeviceToDevice, stream);
    hipMemcpyAsync(vall + 8388608, pv + 4194304, 16777216u, hipMemcpyDeviceToDevice, stream);

    // fp32 -> bf16 pre-pass for x and the QKV weights (wo converted later)
    cvt_kernel<<<1024, 256, 0, stream>>>(x, xb, 2097152);
    cvt3_kernel<<<dim3(512, 3), 256, 0, stream>>>(wq, wk, wv, wqb, wkb, wvb, 1048576);

    // fused QKV projection: Q -> qbf (bf16, pre-scaled), K/V -> kall/vall fp32
    gemm_kernel<1><<<dim3(48, 32), 256, 0, stream>>>(xb, wqb, wkb, wvb,
                                                     qbf, kall, vall, nullptr);
    // K convert+swizzle and V transpose+swizzle prep (weights now dead)
    prep_kv<<<dim3(64, 16, 2), 256, 0, stream>>>(kall, vall, ktg, vtg);
    // MFMA flash attention (bh on x for XCD L2 locality; all-DMA staging;
    // swapped QK^T lane-local softmax)
    attn_mfma<<<dim3(32, 32), 256, 0, stream>>>(qbf, ktg, vtg, ot);
    // wo conversion (vtg now dead) + output projection -> out (fp32)
    cvt_kernel<<<512, 256, 0, stream>>>(wo, wob, 1048576);
    gemm_kernel<0><<<dim3(16, 32), 256, 0, stream>>>(ot, wob, wob, wob,
                                                     nullptr, nullptr, nullptr, out);
}